// Round 3
// baseline (69.731 us; speedup 1.0000x reference)
//
#include <hip/hip_runtime.h>

#define NUM_EXPERTS 64
#define CAPACITY    320
#define NUM_TOKENS  16384
#define EMBED_DIM   2048
#define CHUNK       256
#define NUM_CHUNKS  (NUM_TOKENS / CHUNK)      // 64
#define NUM_SLOTS   (NUM_EXPERTS * CAPACITY)  // 20480

typedef float f32x4 __attribute__((ext_vector_type(4)));

// ---------------------------------------------------------------------------
// ws layout (ints):
//   [0     ..  4096)  counts[chunk][expert]
//   [4096  ..  8192)  offsets[chunk][expert]  (exclusive scan over chunks, per expert)
//   [8192  .. 28672)  slot_token[NUM_SLOTS]   (-1 = empty)
// ---------------------------------------------------------------------------

__global__ void k_hist(const int* __restrict__ expert_ids,
                       int* __restrict__ counts) {
    __shared__ int h[NUM_EXPERTS];
    int t = threadIdx.x;
    if (t < NUM_EXPERTS) h[t] = 0;
    __syncthreads();
    int e = expert_ids[blockIdx.x * CHUNK + t];
    atomicAdd(&h[e], 1);
    __syncthreads();
    if (t < NUM_EXPERTS) counts[blockIdx.x * NUM_EXPERTS + t] = h[t];
}

// 1024 threads: stage all counts into LDS coalesced, fill slot_token=-1,
// then wave 0 does the 64-expert serial scan from LDS (fast, no global
// latency chain) and reduces the per-expert overflow into tokens_dropped.
__global__ void k_scan(const int* __restrict__ counts,
                       int* __restrict__ offsets,
                       int* __restrict__ slot_token,
                       float* __restrict__ out_dropped) {
    __shared__ int sc[NUM_CHUNKS * NUM_EXPERTS];
    int t = threadIdx.x;
    for (int i = t; i < NUM_CHUNKS * NUM_EXPERTS; i += 1024) sc[i] = counts[i];
    for (int i = t; i < NUM_SLOTS; i += 1024) slot_token[i] = -1;
    __syncthreads();
    if (t < NUM_EXPERTS) {
        int run = 0;
        for (int b = 0; b < NUM_CHUNKS; ++b) {
            offsets[b * NUM_EXPERTS + t] = run;
            run += sc[b * NUM_EXPERTS + t];
        }
        int dropped = run > CAPACITY ? run - CAPACITY : 0;
        #pragma unroll
        for (int off = 32; off > 0; off >>= 1)
            dropped += __shfl_down(dropped, off);
        if (t == 0) out_dropped[0] = (float)dropped;
    }
}

__global__ void k_scatter(const int* __restrict__ expert_ids,
                          const int* __restrict__ offsets,
                          int* __restrict__ slot_token) {
    __shared__ int eids[CHUNK];
    int t = threadIdx.x;
    int tok = blockIdx.x * CHUNK + t;
    int e = expert_ids[tok];
    eids[t] = e;
    __syncthreads();
    // stable within-chunk rank among same-expert tokens (token order)
    int rank = 0;
    for (int j = 0; j < t; ++j) rank += (eids[j] == e);
    int pos = offsets[blockIdx.x * NUM_EXPERTS + e] + rank;
    if (pos < CAPACITY) slot_token[e * CAPACITY + pos] = tok;
}

// one block per slot: writes every dispatched_x element exactly once, plus
// this slot's combine_weight and token_index (so no init pass is needed).
__global__ void k_gather(const float* __restrict__ x,
                         const float* __restrict__ weights,
                         const int* __restrict__ slot_token,
                         float* __restrict__ out_x,
                         float* __restrict__ out_combine,
                         float* __restrict__ out_tokidx) {
    int slot = blockIdx.x;
    int tok  = slot_token[slot];
    int t    = threadIdx.x;            // 256 threads, 2 float4 each
    f32x4* dst = (f32x4*)(out_x + (size_t)slot * EMBED_DIM);
    if (tok >= 0) {
        const f32x4* src = (const f32x4*)(x + (size_t)tok * EMBED_DIM);
        f32x4 a = __builtin_nontemporal_load(src + t);
        f32x4 b = __builtin_nontemporal_load(src + t + 256);
        __builtin_nontemporal_store(a, dst + t);
        __builtin_nontemporal_store(b, dst + t + 256);
        if (t == 0) {
            out_combine[slot] = weights[tok];
            out_tokidx[slot]  = (float)tok;
        }
    } else {
        f32x4 z = {0.f, 0.f, 0.f, 0.f};
        __builtin_nontemporal_store(z, dst + t);
        __builtin_nontemporal_store(z, dst + t + 256);
        if (t == 0) {
            out_combine[slot] = 0.0f;
            out_tokidx[slot]  = -1.0f;
        }
    }
}

extern "C" void kernel_launch(void* const* d_in, const int* in_sizes, int n_in,
                              void* d_out, int out_size, void* d_ws, size_t ws_size,
                              hipStream_t stream) {
    const float* x          = (const float*)d_in[0];
    const int*   expert_ids = (const int*)d_in[1];
    const float* weights    = (const float*)d_in[2];

    float* out         = (float*)d_out;
    float* out_x       = out;
    float* out_combine = out + (size_t)NUM_SLOTS * EMBED_DIM;
    float* out_tokidx  = out_combine + NUM_SLOTS;
    float* out_dropped = out_tokidx  + NUM_SLOTS;

    int* counts     = (int*)d_ws;
    int* offsets    = counts  + NUM_CHUNKS * NUM_EXPERTS;
    int* slot_token = offsets + NUM_CHUNKS * NUM_EXPERTS;

    k_hist<<<NUM_CHUNKS, CHUNK, 0, stream>>>(expert_ids, counts);
    k_scan<<<1, 1024, 0, stream>>>(counts, offsets, slot_token, out_dropped);
    k_scatter<<<NUM_CHUNKS, CHUNK, 0, stream>>>(expert_ids, offsets, slot_token);
    k_gather<<<NUM_SLOTS, 256, 0, stream>>>(x, weights, slot_token,
                                            out_x, out_combine, out_tokidx);
}

// Round 4
// 64.664 us; speedup vs baseline: 1.0784x; 1.0784x over previous
//
#include <hip/hip_runtime.h>

#define NUM_EXPERTS 64
#define CAPACITY    320
#define NUM_TOKENS  16384
#define EMBED_DIM   2048
#define CHUNK       256
#define NUM_CHUNKS  (NUM_TOKENS / CHUNK)      // 64
#define NUM_SLOTS   (NUM_EXPERTS * CAPACITY)  // 20480

typedef float f32x4 __attribute__((ext_vector_type(4)));

// ---------------------------------------------------------------------------
// ws layout (ints):
//   [0     ..  4096)  counts[chunk][expert]
//   [4096  ..  8192)  offsets[chunk][expert]  (exclusive scan over chunks, per expert)
//   [8192  .. 28672)  slot_token[NUM_SLOTS]   (-1 = empty)
// ---------------------------------------------------------------------------

__global__ void k_hist(const int* __restrict__ expert_ids,
                       int* __restrict__ counts) {
    __shared__ int h[NUM_EXPERTS];
    int t = threadIdx.x;
    if (t < NUM_EXPERTS) h[t] = 0;
    __syncthreads();
    int e = expert_ids[blockIdx.x * CHUNK + t];
    atomicAdd(&h[e], 1);
    __syncthreads();
    if (t < NUM_EXPERTS) counts[blockIdx.x * NUM_EXPERTS + t] = h[t];
}

// 1024 threads: stage all counts into LDS coalesced, fill slot_token=-1,
// then wave 0 does the 64-expert serial scan from LDS (no global latency
// chain) and reduces the per-expert overflow into tokens_dropped.
__global__ void k_scan(const int* __restrict__ counts,
                       int* __restrict__ offsets,
                       int* __restrict__ slot_token,
                       float* __restrict__ out_dropped) {
    __shared__ int sc[NUM_CHUNKS * NUM_EXPERTS];
    int t = threadIdx.x;
    for (int i = t; i < NUM_CHUNKS * NUM_EXPERTS; i += 1024) sc[i] = counts[i];
    for (int i = t; i < NUM_SLOTS; i += 1024) slot_token[i] = -1;
    __syncthreads();
    if (t < NUM_EXPERTS) {
        int run = 0;
        for (int b = 0; b < NUM_CHUNKS; ++b) {
            offsets[b * NUM_EXPERTS + t] = run;
            run += sc[b * NUM_EXPERTS + t];
        }
        int dropped = run > CAPACITY ? run - CAPACITY : 0;
        #pragma unroll
        for (int off = 32; off > 0; off >>= 1)
            dropped += __shfl_down(dropped, off);
        if (t == 0) out_dropped[0] = (float)dropped;
    }
}

__global__ void k_scatter(const int* __restrict__ expert_ids,
                          const int* __restrict__ offsets,
                          int* __restrict__ slot_token) {
    __shared__ int eids[CHUNK];
    int t = threadIdx.x;
    int tok = blockIdx.x * CHUNK + t;
    int e = expert_ids[tok];
    eids[t] = e;
    __syncthreads();
    // stable within-chunk rank among same-expert tokens (token order)
    int rank = 0;
    for (int j = 0; j < t; ++j) rank += (eids[j] == e);
    int pos = offsets[blockIdx.x * NUM_EXPERTS + e] + rank;
    if (pos < CAPACITY) slot_token[e * CAPACITY + pos] = tok;
}

// one block per slot: writes every dispatched_x element exactly once, plus
// this slot's combine_weight and token_index (so no init pass is needed).
__global__ void k_gather(const float* __restrict__ x,
                         const float* __restrict__ weights,
                         const int* __restrict__ slot_token,
                         float* __restrict__ out_x,
                         float* __restrict__ out_combine,
                         float* __restrict__ out_tokidx) {
    int slot = blockIdx.x;
    int tok  = slot_token[slot];
    int t    = threadIdx.x;            // 256 threads, 2 float4 each
    f32x4* dst = (f32x4*)(out_x + (size_t)slot * EMBED_DIM);
    if (tok >= 0) {
        const f32x4* src = (const f32x4*)(x + (size_t)tok * EMBED_DIM);
        dst[t]       = src[t];
        dst[t + 256] = src[t + 256];
        if (t == 0) {
            out_combine[slot] = weights[tok];
            out_tokidx[slot]  = (float)tok;
        }
    } else {
        f32x4 z = {0.f, 0.f, 0.f, 0.f};
        dst[t]       = z;
        dst[t + 256] = z;
        if (t == 0) {
            out_combine[slot] = 0.0f;
            out_tokidx[slot]  = -1.0f;
        }
    }
}

extern "C" void kernel_launch(void* const* d_in, const int* in_sizes, int n_in,
                              void* d_out, int out_size, void* d_ws, size_t ws_size,
                              hipStream_t stream) {
    const float* x          = (const float*)d_in[0];
    const int*   expert_ids = (const int*)d_in[1];
    const float* weights    = (const float*)d_in[2];

    float* out         = (float*)d_out;
    float* out_x       = out;
    float* out_combine = out + (size_t)NUM_SLOTS * EMBED_DIM;
    float* out_tokidx  = out_combine + NUM_SLOTS;
    float* out_dropped = out_tokidx  + NUM_SLOTS;

    int* counts     = (int*)d_ws;
    int* offsets    = counts  + NUM_CHUNKS * NUM_EXPERTS;
    int* slot_token = offsets + NUM_CHUNKS * NUM_EXPERTS;

    k_hist<<<NUM_CHUNKS, CHUNK, 0, stream>>>(expert_ids, counts);
    k_scan<<<1, 1024, 0, stream>>>(counts, offsets, slot_token, out_dropped);
    k_scatter<<<NUM_CHUNKS, CHUNK, 0, stream>>>(expert_ids, offsets, slot_token);
    k_gather<<<NUM_SLOTS, 256, 0, stream>>>(x, weights, slot_token,
                                            out_x, out_combine, out_tokidx);
}

// Round 5
// 59.261 us; speedup vs baseline: 1.1767x; 1.0912x over previous
//
#include <hip/hip_runtime.h>

#define NUM_EXPERTS 64
#define CAPACITY    320
#define NUM_TOKENS  16384
#define EMBED_DIM   2048
#define CHUNK       256
#define NUM_CHUNKS  (NUM_TOKENS / CHUNK)      // 64
#define NUM_SLOTS   (NUM_EXPERTS * CAPACITY)  // 20480

typedef float f32x4 __attribute__((ext_vector_type(4)));

// ws layout (ints): offsets[NUM_CHUNKS][NUM_EXPERTS] | totals[NUM_EXPERTS]

// Single block: histogram (LDS atomics) -> per-expert exclusive scan over
// chunks -> offsets, totals, tokens_dropped. Replaces hist+scan+scatter.
__global__ void k_prelude(const int* __restrict__ ids,
                          int* __restrict__ offsets,
                          int* __restrict__ totals,
                          float* __restrict__ out_dropped) {
    __shared__ int cnt[NUM_CHUNKS][NUM_EXPERTS];   // 16 KB
    int t = threadIdx.x;                           // 1024 threads
    for (int i = t; i < NUM_CHUNKS * NUM_EXPERTS; i += 1024)
        ((int*)cnt)[i] = 0;
    __syncthreads();
    #pragma unroll
    for (int r = 0; r < NUM_TOKENS / 1024; ++r) {
        int idx = r * 1024 + t;
        atomicAdd(&cnt[idx >> 8][ids[idx]], 1);
    }
    __syncthreads();
    if (t < NUM_EXPERTS) {
        int run = 0;
        for (int b = 0; b < NUM_CHUNKS; ++b) {
            offsets[b * NUM_EXPERTS + t] = run;
            run += cnt[b][t];
        }
        totals[t] = run;
        int dropped = run > CAPACITY ? run - CAPACITY : 0;
        #pragma unroll
        for (int off = 32; off > 0; off >>= 1)
            dropped += __shfl_down(dropped, off);
        if (t == 0) out_dropped[0] = (float)dropped;
    }
}

// Blocks [0, NUM_TOKENS): token-major copy — sequential x reads, scattered
//   slot writes. Stable rank via per-wave ballot popcount over chunk ids.
// Blocks [NUM_TOKENS, NUM_TOKENS+NUM_SLOTS): slot-major zero-fill of empty
//   slots (early-exit when filled). Interleaves with the copy blocks.
__global__ void k_dispatch(const float* __restrict__ x,
                           const int* __restrict__ ids,
                           const float* __restrict__ weights,
                           const int* __restrict__ offsets,
                           const int* __restrict__ totals,
                           float* __restrict__ out_x,
                           float* __restrict__ out_combine,
                           float* __restrict__ out_tokidx) {
    int bid = blockIdx.x;
    int t   = threadIdx.x;                 // 256 threads
    if (bid < NUM_TOKENS) {
        int tok = bid;
        const f32x4* src = (const f32x4*)(x + (size_t)tok * EMBED_DIM);
        f32x4 a = src[t];                  // issue row loads first
        f32x4 b = src[t + 256];
        int c = tok >> 8, tp = tok & 255;
        __shared__ int eids[CHUNK];
        __shared__ unsigned long long wmask[4];
        eids[t] = ids[c * CHUNK + t];
        __syncthreads();
        int e = eids[tp];
        unsigned long long m = __ballot((t < tp) && (eids[t] == e));
        if ((t & 63) == 0) wmask[t >> 6] = m;
        __syncthreads();
        int rank = __popcll(wmask[0]) + __popcll(wmask[1])
                 + __popcll(wmask[2]) + __popcll(wmask[3]);
        int pos = offsets[c * NUM_EXPERTS + e] + rank;
        if (pos >= CAPACITY) return;       // dropped token (block-uniform)
        size_t slot = (size_t)e * CAPACITY + pos;
        f32x4* dst = (f32x4*)(out_x + slot * EMBED_DIM);
        dst[t]       = a;
        dst[t + 256] = b;
        if (t == 0) {
            out_combine[slot] = weights[tok];
            out_tokidx[slot]  = (float)tok;
        }
    } else {
        int s   = bid - NUM_TOKENS;        // slot id
        int e   = s / CAPACITY;
        int pos = s - e * CAPACITY;
        if (pos < totals[e]) return;       // filled by a token block
        f32x4* dst = (f32x4*)(out_x + (size_t)s * EMBED_DIM);
        f32x4 z = {0.f, 0.f, 0.f, 0.f};
        dst[t]       = z;
        dst[t + 256] = z;
        if (t == 0) {
            out_combine[s] = 0.0f;
            out_tokidx[s]  = -1.0f;
        }
    }
}

extern "C" void kernel_launch(void* const* d_in, const int* in_sizes, int n_in,
                              void* d_out, int out_size, void* d_ws, size_t ws_size,
                              hipStream_t stream) {
    const float* x          = (const float*)d_in[0];
    const int*   expert_ids = (const int*)d_in[1];
    const float* weights    = (const float*)d_in[2];

    float* out         = (float*)d_out;
    float* out_x       = out;
    float* out_combine = out + (size_t)NUM_SLOTS * EMBED_DIM;
    float* out_tokidx  = out_combine + NUM_SLOTS;
    float* out_dropped = out_tokidx  + NUM_SLOTS;

    int* offsets = (int*)d_ws;
    int* totals  = offsets + NUM_CHUNKS * NUM_EXPERTS;

    k_prelude<<<1, 1024, 0, stream>>>(expert_ids, offsets, totals, out_dropped);
    k_dispatch<<<NUM_TOKENS + NUM_SLOTS, 256, 0, stream>>>(
        x, expert_ids, weights, offsets, totals,
        out_x, out_combine, out_tokidx);
}